// Round 2
// baseline (168.390 us; speedup 1.0000x reference)
//
#include <hip/hip_runtime.h>

// Problem constants (from reference):
//   B=2048, T=128, I=130, H=10, 3H=30, D1=20
// Inputs (dict order):
//   0 ru [B,T,130]  1 en [B,T,130]
//   2 ru_Wih [30,130] 3 ru_Whh [30,10] 4 ru_bih [30] 5 ru_bhh [30]
//   6 en_Wih [30,130] 7 en_Whh [30,10] 8 en_bih [30] 9 en_bhh [30]
//   10 W1 [20,20] 11 b1 [20] 12 W2 [1,20] 13 b2 [1]
// Output: [B,1] f32 (2048 floats)
//
// Design: 1 wave per (gru, batch) chain. 4096 waves = 1024 blocks x 256 thr.
// Lane layout: g = lane&31 (gate, 30 active), h = lane>>5 (half of I-dim).
// Wih row-half hoisted to ~65 VGPRs per lane; x row staged to per-wave LDS
// each timestep (broadcast ds_read_b128 by gate lanes). MLP tail fused via
// v = W2@W1 and atomicAdd into out[b] (2 commutative adds -> deterministic).
//
// Round-1 bug fixed here: x[128..129] were never staged (guard `lane<66`
// can't cover 66 elements with 64 lanes). Now a third element xc (lanes 0,1)
// stages lbuf[128..129].

#define BB 2048
#define TT 128
#define II 130
#define HH 10

__device__ __forceinline__ float sigmoidf_fast(float x) {
    return __fdividef(1.f, 1.f + __expf(-x));
}
__device__ __forceinline__ float tanhf_fast(float x) {
    float ax = fabsf(x);
    float e = __expf(-2.f * ax);
    float t = __fdividef(1.f - e, 1.f + e);
    return copysignf(t, x);
}

__global__ __launch_bounds__(256, 4)
void gru_fused(const float* __restrict__ ru, const float* __restrict__ en,
               const float* __restrict__ ruWih, const float* __restrict__ ruWhh,
               const float* __restrict__ rubih, const float* __restrict__ rubhh,
               const float* __restrict__ enWih, const float* __restrict__ enWhh,
               const float* __restrict__ enbih, const float* __restrict__ enbhh,
               const float* __restrict__ W1, const float* __restrict__ b1,
               const float* __restrict__ W2, const float* __restrict__ b2,
               float* __restrict__ out)
{
    const int tid  = threadIdx.x;
    const int wv   = tid >> 6;        // wave in block 0..3
    const int lane = tid & 63;
    const int g    = lane & 31;       // gate index (0..29 active)
    const int h    = lane >> 5;       // input-dim half 0/1
    const int wid  = blockIdx.x * 4 + wv;
    const int gru  = wid >> 11;       // 0 = ru, 1 = en
    const int b    = wid & (BB - 1);

    const float* __restrict__ x   = gru ? en    : ru;
    const float* __restrict__ Wih = gru ? enWih : ruWih;
    const float* __restrict__ Whh = gru ? enWhh : ruWhh;
    const float* __restrict__ bih = gru ? enbih : rubih;
    const float* __restrict__ bhh = gru ? enbhh : rubhh;

    __shared__ float lds[4][132];     // per-wave x-row buffer (132*4B = 16B-mult)
    float* lbuf = lds[wv];

    // ---- hoist weights into registers (once per wave) ----
    const int gq = (g < 30) ? g : 0;  // clamp inactive lanes
    float wih[64];
    #pragma unroll
    for (int j = 0; j < 64; ++j) wih[j] = Wih[gq * II + h * 64 + j];
    const float w_e = Wih[gq * II + 128 + h];       // i=128 (h=0) / i=129 (h=1)
    float whh[HH];
    #pragma unroll
    for (int k = 0; k < HH; ++k) whh[k] = Whh[gq * HH + k];
    const float bihg = bih[gq];
    const float bhhg = bhh[gq];

    float hreg[HH];                    // replicated h state (static indexing only)
    #pragma unroll
    for (int k = 0; k < HH; ++k) hreg[k] = 0.f;
    float hown = 0.f;                  // n-lane (g=20+k) keeps its own h[k]

    const float* __restrict__ xrow = x + (size_t)b * (TT * II);

    // prefetch t = 0 : 64 + 64 + 2 elements
    float xa = xrow[lane];
    float xb = xrow[64 + lane];
    float xc = (lane < 2) ? xrow[128 + lane] : 0.f;

    for (int t = 0; t < TT; ++t) {
        // stage x row to this wave's LDS slice (intra-wave ordering is FIFO)
        lbuf[lane] = xa;
        lbuf[64 + lane] = xb;
        if (lane < 2) lbuf[128 + lane] = xc;

        // prefetch t+1 while we compute t
        if (t + 1 < TT) {
            const float* __restrict__ xn = xrow + (size_t)(t + 1) * II;
            xa = xn[lane];
            xb = xn[64 + lane];
            xc = (lane < 2) ? xn[128 + lane] : 0.f;
        }

        // xi half-dot: 64 fma from broadcast LDS reads
        float s = 0.f;
        const float4* lb4 = (const float4*)(lbuf + h * 64);
        #pragma unroll
        for (int c = 0; c < 16; ++c) {
            float4 v = lb4[c];
            s = fmaf(wih[4 * c + 0], v.x, s);
            s = fmaf(wih[4 * c + 1], v.y, s);
            s = fmaf(wih[4 * c + 2], v.z, s);
            s = fmaf(wih[4 * c + 3], v.w, s);
        }
        s = fmaf(w_e, lbuf[128 + h], s);
        s += __shfl_xor(s, 32);        // combine halves: full xi pre-bias in both halves

        // recurrent projection gh[g] = Whh[g,:] . h + bhh[g]
        float gh = bhhg;
        #pragma unroll
        for (int k = 0; k < HH; ++k) gh = fmaf(whh[k], hreg[k], gh);

        const float xi  = s + bihg;
        const float pre = xi + gh;     // r-pre in lanes g<10, z-pre in lanes 10..19

        // n lanes (g = 20+k) assemble the update; uniform execution, garbage elsewhere
        const float rpre = __shfl(pre, (g - 20) & 31);  // from lane k     (half 0)
        const float zpre = __shfl(pre, (g - 10) & 31);  // from lane 10+k (half 0)
        const float r = sigmoidf_fast(rpre);
        const float z = sigmoidf_fast(zpre);
        const float n = tanhf_fast(xi + r * gh);
        const float hnew = (1.f - z) * n + z * hown;
        hown = hnew;

        // broadcast new h from lanes 20..29 to everyone's replicated copy
        #pragma unroll
        for (int k = 0; k < HH; ++k) hreg[k] = __shfl(hnew, 20 + k);
    }

    // ---- fused MLP tail: out[b] = sum_j v[j]*grus_out[j] + c,  v = W2@W1 ----
    float val = 0.f;
    if (h == 0 && g >= 20 && g < 30) { // lane 20+k holds h[k] in hown (static!)
        const int k = g - 20;
        float v = 0.f;
        #pragma unroll
        for (int d = 0; d < 20; ++d)
            v = fmaf(W2[d], W1[d * 20 + gru * 10 + k], v);
        val = v * hown;
        if (g == 20 && gru == 0) {     // constant term added exactly once per b
            float c = b2[0];
            #pragma unroll
            for (int d = 0; d < 20; ++d) c = fmaf(W2[d], b1[d], c);
            val += c;
        }
    }
    #pragma unroll
    for (int o = 32; o > 0; o >>= 1) val += __shfl_xor(val, o);
    if (lane == 0) atomicAdd(&out[b], val);   // 2 commutative f32 adds -> deterministic
}

extern "C" void kernel_launch(void* const* d_in, const int* in_sizes, int n_in,
                              void* d_out, int out_size, void* d_ws, size_t ws_size,
                              hipStream_t stream) {
    (void)in_sizes; (void)n_in; (void)d_ws; (void)ws_size;
    const float* ru    = (const float*)d_in[0];
    const float* en    = (const float*)d_in[1];
    const float* ruWih = (const float*)d_in[2];
    const float* ruWhh = (const float*)d_in[3];
    const float* rubih = (const float*)d_in[4];
    const float* rubhh = (const float*)d_in[5];
    const float* enWih = (const float*)d_in[6];
    const float* enWhh = (const float*)d_in[7];
    const float* enbih = (const float*)d_in[8];
    const float* enbhh = (const float*)d_in[9];
    const float* W1    = (const float*)d_in[10];
    const float* b1    = (const float*)d_in[11];
    const float* W2    = (const float*)d_in[12];
    const float* b2    = (const float*)d_in[13];
    float* out = (float*)d_out;

    hipMemsetAsync(d_out, 0, (size_t)out_size * sizeof(float), stream);
    // 2 GRUs x 2048 chains = 4096 waves; 4 waves/block -> 1024 blocks
    gru_fused<<<dim3(1024), dim3(256), 0, stream>>>(
        ru, en, ruWih, ruWhh, rubih, rubhh,
        enWih, enWhh, enbih, enbhh, W1, b1, W2, b2, out);
}

// Round 3
// 143.654 us; speedup vs baseline: 1.1722x; 1.1722x over previous
//
#include <hip/hip_runtime.h>

// B=2048, T=128, I=130, H=10, 3H=30, D1=20
// One wave per (gru, batch) chain: 4096 waves = 1024 blocks x 256 threads.
// Lane layout: g = lane&31 (gate 0..29), h = lane>>5 (I-dim half).
// Round-3 changes vs round-2:
//  - h-state + gate pre-activations moved to per-wave LDS (in-order DS within
//    a wave; replaces 12 ds_bpermute shuffles) -> fewer VALU insts, shorter
//    register live set (hreg[10] gone) so wih[64] fits in VGPRs (no AGPR
//    spill moves, which were ~half of round-2's 296 VALU insts/step).
//  - dot product uses 4 accumulators, gh uses 2 (break serial fma chains).
//  - branchless prefetch clamp.

#define BB 2048
#define TT 128
#define II 130

__device__ __forceinline__ float sigmoidf_fast(float x) {
    return __fdividef(1.f, 1.f + __expf(-x));
}
__device__ __forceinline__ float tanhf_fast(float x) {
    float ax = fabsf(x);
    float e = __expf(-2.f * ax);
    float t = __fdividef(1.f - e, 1.f + e);
    return copysignf(t, x);
}

__global__ __launch_bounds__(256, 4)
void gru_fused(const float* __restrict__ ru, const float* __restrict__ en,
               const float* __restrict__ ruWih, const float* __restrict__ ruWhh,
               const float* __restrict__ rubih, const float* __restrict__ rubhh,
               const float* __restrict__ enWih, const float* __restrict__ enWhh,
               const float* __restrict__ enbih, const float* __restrict__ enbhh,
               const float* __restrict__ W1, const float* __restrict__ b1,
               const float* __restrict__ W2, const float* __restrict__ b2,
               float* __restrict__ out)
{
    const int tid  = threadIdx.x;
    const int wv   = tid >> 6;
    const int lane = tid & 63;
    const int g    = lane & 31;       // gate index (0..29 active)
    const int h    = lane >> 5;       // input-dim half 0/1
    const int wid  = blockIdx.x * 4 + wv;
    const int gru  = wid >> 11;       // 0 = ru, 1 = en
    const int b    = wid & (BB - 1);

    const float* __restrict__ x   = gru ? en    : ru;
    const float* __restrict__ Wih = gru ? enWih : ruWih;
    const float* __restrict__ Whh = gru ? enWhh : ruWhh;
    const float* __restrict__ bih = gru ? enbih : rubih;
    const float* __restrict__ bhh = gru ? enbhh : rubhh;

    // per-wave LDS: x[132] | pre[32] | h[12]  (176 floats = 704 B, 16B-mult)
    __shared__ __align__(16) float lds[4][176];
    float* __restrict__ X    = lds[wv];
    float* __restrict__ PRE  = X + 132;
    float* __restrict__ Hbuf = X + 164;

    // ---- hoist weights into registers (once per wave) ----
    const int gq = (g < 30) ? g : 0;
    float wih[64];
    #pragma unroll
    for (int j = 0; j < 64; ++j) wih[j] = Wih[gq * II + h * 64 + j];
    const float w_e = Wih[gq * II + 128 + h];
    float whh[10];
    #pragma unroll
    for (int k = 0; k < 10; ++k) whh[k] = Whh[gq * 10 + k];
    const float bihg = bih[gq];
    const float bhhg = bhh[gq];

    if (lane < 12) Hbuf[lane] = 0.f;   // h0 = 0 (in-order DS within the wave)
    float hown = 0.f;                  // n-lane (g=20+k, h=0) tracks its own h[k]

    const float* __restrict__ xrow = x + (size_t)b * (TT * II);

    // prefetch t=0
    float xa = xrow[lane];
    float xb = xrow[64 + lane];
    float xc = (lane < 2) ? xrow[128 + lane] : 0.f;

    for (int t = 0; t < TT; ++t) {
        // stage x row (intra-wave FIFO ordering; no barrier needed)
        X[lane] = xa;
        X[64 + lane] = xb;
        if (lane < 2) X[128 + lane] = xc;

        // branchless prefetch of next row (last iter re-reads row 127)
        {
            const int tn = (t < TT - 1) ? t + 1 : t;
            const float* __restrict__ xn = xrow + (size_t)tn * II;
            xa = xn[lane];
            xb = xn[64 + lane];
            xc = (lane < 2) ? xn[128 + lane] : 0.f;
        }

        // recurrent projection from LDS h (broadcast reads, 2-acc chain)
        const float4 h03 = *(const float4*)(Hbuf);
        const float4 h47 = *(const float4*)(Hbuf + 4);
        const float2 h89 = *(const float2*)(Hbuf + 8);
        float gh0 = fmaf(whh[0], h03.x, bhhg);
        float gh1 = whh[1] * h03.y;
        gh0 = fmaf(whh[2], h03.z, gh0);
        gh1 = fmaf(whh[3], h03.w, gh1);
        gh0 = fmaf(whh[4], h47.x, gh0);
        gh1 = fmaf(whh[5], h47.y, gh1);
        gh0 = fmaf(whh[6], h47.z, gh0);
        gh1 = fmaf(whh[7], h47.w, gh1);
        gh0 = fmaf(whh[8], h89.x, gh0);
        gh1 = fmaf(whh[9], h89.y, gh1);
        const float gh = gh0 + gh1;

        // xi half-dot: 64 fma, 4 accumulators, broadcast b128 LDS reads
        float s0 = 0.f, s1 = 0.f, s2 = 0.f, s3 = 0.f;
        const float4* __restrict__ xb4 = (const float4*)(X + h * 64);
        #pragma unroll
        for (int c = 0; c < 16; ++c) {
            const float4 v = xb4[c];
            s0 = fmaf(wih[4 * c + 0], v.x, s0);
            s1 = fmaf(wih[4 * c + 1], v.y, s1);
            s2 = fmaf(wih[4 * c + 2], v.z, s2);
            s3 = fmaf(wih[4 * c + 3], v.w, s3);
        }
        float s = (s0 + s1) + (s2 + s3);
        s = fmaf(w_e, X[128 + h], s);
        s += __shfl_xor(s, 32);        // combine halves (only remaining shuffle)

        const float xi  = s + bihg;
        const float pre = xi + gh;

        if (lane < 30) PRE[lane] = pre;          // h=0 gate lanes publish
        const float rpre = PRE[(g - 20) & 31];   // n-lane g=20+k -> pre[k]
        const float zpre = PRE[(g - 10) & 31];   // n-lane g=20+k -> pre[10+k]

        const float r = sigmoidf_fast(rpre);
        const float z = sigmoidf_fast(zpre);
        const float n = tanhf_fast(xi + r * gh);
        const float hnew = (1.f - z) * n + z * hown;
        hown = hnew;

        if (lane >= 20 && lane < 30) Hbuf[lane - 20] = hnew;  // publish new h
    }

    // ---- fused MLP tail: out[b] += sum_k v[k]*h[k] (+ const once) ----
    float val = 0.f;
    if (lane < 10) {
        const float hk = Hbuf[lane];             // final h from LDS
        float v = 0.f;
        #pragma unroll
        for (int d = 0; d < 20; ++d)
            v = fmaf(W2[d], W1[d * 20 + gru * 10 + lane], v);
        val = v * hk;
        if (lane == 0 && gru == 0) {
            float c = b2[0];
            #pragma unroll
            for (int d = 0; d < 20; ++d) c = fmaf(W2[d], b1[d], c);
            val += c;
        }
    }
    #pragma unroll
    for (int o = 32; o > 0; o >>= 1) val += __shfl_xor(val, o);
    if (lane == 0) atomicAdd(&out[b], val);      // 2 commutative adds / output
}

extern "C" void kernel_launch(void* const* d_in, const int* in_sizes, int n_in,
                              void* d_out, int out_size, void* d_ws, size_t ws_size,
                              hipStream_t stream) {
    (void)in_sizes; (void)n_in; (void)d_ws; (void)ws_size;
    const float* ru    = (const float*)d_in[0];
    const float* en    = (const float*)d_in[1];
    const float* ruWih = (const float*)d_in[2];
    const float* ruWhh = (const float*)d_in[3];
    const float* rubih = (const float*)d_in[4];
    const float* rubhh = (const float*)d_in[5];
    const float* enWih = (const float*)d_in[6];
    const float* enWhh = (const float*)d_in[7];
    const float* enbih = (const float*)d_in[8];
    const float* enbhh = (const float*)d_in[9];
    const float* W1    = (const float*)d_in[10];
    const float* b1    = (const float*)d_in[11];
    const float* W2    = (const float*)d_in[12];
    const float* b2    = (const float*)d_in[13];
    float* out = (float*)d_out;

    hipMemsetAsync(d_out, 0, (size_t)out_size * sizeof(float), stream);
    gru_fused<<<dim3(1024), dim3(256), 0, stream>>>(
        ru, en, ruWih, ruWhh, rubih, rubhh,
        enWih, enWhh, enbih, enbhh, W1, b1, W2, b2, out);
}